// Round 5
// baseline (231.040 us; speedup 1.0000x reference)
//
#include <hip/hip_runtime.h>
#include <stdint.h>

// Problem constants
#define R_DIM 1024
#define B_DIM 16
#define D_DIM 256
#define S_DIM 20

typedef float f32x4 __attribute__((ext_vector_type(4)));

// ---------------------------------------------------------------------------
// JAX threefry2x32, key = [0, 1234], partitionable counter scheme:
// for flat index i: x0 = 0, x1 = i; bits = o0 ^ o1.
// ---------------------------------------------------------------------------
__device__ __forceinline__ void threefry2x32_1234(uint32_t x0, uint32_t x1,
                                                  uint32_t& o0, uint32_t& o1) {
  const uint32_t ks1 = 1234u;
  const uint32_t ks2 = 1234u ^ 0x1BD11BDAu;
  x1 += ks1;  // x0 += ks0 (=0)
#define TF_ROUND(r) { x0 += x1; x1 = (x1 << (r)) | (x1 >> (32 - (r))); x1 ^= x0; }
  TF_ROUND(13) TF_ROUND(15) TF_ROUND(26) TF_ROUND(6)
  x0 += ks1; x1 += ks2 + 1u;
  TF_ROUND(17) TF_ROUND(29) TF_ROUND(16) TF_ROUND(24)
  x0 += ks2; x1 += 2u;  // + ks0 (=0)
  TF_ROUND(13) TF_ROUND(15) TF_ROUND(26) TF_ROUND(6)
  x1 += ks1 + 3u;       // x0 += ks0 (=0)
  TF_ROUND(17) TF_ROUND(29) TF_ROUND(16) TF_ROUND(24)
  x0 += ks1; x1 += ks2 + 4u;
  TF_ROUND(13) TF_ROUND(15) TF_ROUND(26) TF_ROUND(6)
  x0 += ks2; x1 += 5u;  // + ks0 (=0)
#undef TF_ROUND
  o0 = x0; o1 = x1;
}

// 64-lane butterfly max of a uint64 key
__device__ __forceinline__ unsigned long long wave_max_u64(unsigned long long v) {
#pragma unroll
  for (int off = 1; off < 64; off <<= 1) {
    unsigned long long o = __shfl_xor(v, off, 64);
    v = (o > v) ? o : v;
  }
  return v;
}

__device__ __forceinline__ void top5_mask(unsigned long long* keys, uint32_t* idx) {
#pragma unroll
  for (int n = 0; n < 5; ++n) {
    unsigned long long lm = keys[0];
#pragma unroll
    for (int t = 1; t < 16; ++t) lm = (keys[t] > lm) ? keys[t] : lm;
    unsigned long long g = wave_max_u64(lm);
    idx[n] = 0xFFFFFFFFu - (uint32_t)g;
#pragma unroll
    for (int t = 0; t < 16; ++t)
      if (keys[t] == g) keys[t] = 0ull;
  }
}

// ---------------------------------------------------------------------------
// Kernel A: three block ranges, co-resident so VALU-bound threefry blocks
// overlap with memory-bound transpose/gather blocks across CUs.
//   [0,4096)      transpose: out0[r][b][d] = vit[b][d][r]
//   [4096,8192)   top4-gather: out1 rows from lag_feature
//   [8192,12288)  threefry top5 per score-row -> neg_idx[row*5+n] in d_ws
// ---------------------------------------------------------------------------
__global__ __launch_bounds__(256) void kA(const float* __restrict__ vit,
                                          const float* __restrict__ lag_feature,
                                          const float* __restrict__ lag_vit_map,
                                          float* __restrict__ out0,
                                          float* __restrict__ out1,
                                          uint32_t* __restrict__ neg_idx) {
  if (blockIdx.x < 4096) {
    // ---- transpose part: 32x32 tile per block ----
    __shared__ float tile[32][33];
    const int id = blockIdx.x;
    const int bx = id & 31;          // r-tile
    const int by = (id >> 5) & 7;    // d-tile
    const int bz = id >> 8;          // b
    const int r0 = bx * 32, d0 = by * 32;
    const int tx = threadIdx.x & 31, ty = threadIdx.x >> 5;
    const float* src = vit + (size_t)bz * D_DIM * R_DIM;
#pragma unroll
    for (int i = 0; i < 4; ++i) {
      int d = d0 + ty + i * 8;
      tile[ty + i * 8][tx] = src[(size_t)d * R_DIM + r0 + tx];
    }
    __syncthreads();
    if (bz == 15) {
      // re-read by kernel B: keep cached
#pragma unroll
      for (int i = 0; i < 4; ++i) {
        int r = r0 + ty + i * 8;
        out0[((size_t)r * B_DIM + bz) * D_DIM + d0 + tx] = tile[tx][ty + i * 8];
      }
    } else {
      // never re-read: streaming store
#pragma unroll
      for (int i = 0; i < 4; ++i) {
        int r = r0 + ty + i * 8;
        __builtin_nontemporal_store(tile[tx][ty + i * 8],
                                    &out0[((size_t)r * B_DIM + bz) * D_DIM + d0 + tx]);
      }
    }
  } else if (blockIdx.x < 8192) {
    // ---- top4 gather part: one wave per (r,b) row ----
    const int tid = (blockIdx.x - 4096) * 256 + threadIdx.x;
    const int lane = threadIdx.x & 63;
    const int row = tid >> 6;        // r*16 + b
    const int r = row >> 4;
    const int b = row & 15;

    unsigned long long key = 0ull;
    if (lane < S_DIM) {
      float f = lag_vit_map[((size_t)b * S_DIM + lane) * R_DIM + r];
      uint32_t u = __float_as_uint(f);
      uint32_t ok = u ^ (uint32_t)(((int32_t)u >> 31) | 0x80000000u);
      key = ((unsigned long long)ok << 32) | (0xFFFFFFFFu - (uint32_t)lane);
    }

    uint32_t cols[4];
#pragma unroll
    for (int k = 0; k < 4; ++k) {
      unsigned long long m = wave_max_u64(key);
      cols[k] = 0xFFFFFFFFu - (uint32_t)m;
      if (key == m) key = 0ull;
    }

#pragma unroll
    for (int k = 0; k < 4; ++k) {
      const f32x4* src = (const f32x4*)(lag_feature + ((size_t)b * S_DIM + cols[k]) * D_DIM);
      f32x4* dst = (f32x4*)(out1 + ((size_t)row * 4 + k) * D_DIM);
      __builtin_nontemporal_store(src[lane], &dst[lane]);
    }
  } else {
    // ---- threefry + top5 index part: one wave per score-row ----
    const int tid = (blockIdx.x - 8192) * 256 + threadIdx.x;
    const int lane = threadIdx.x & 63;
    const int row = tid >> 6;        // r*16 + b
    const int r = row >> 4, b = row & 15;

    unsigned long long keys[16];
    const uint32_t base = (uint32_t)row * 1024u;
#pragma unroll
    for (int t = 0; t < 16; ++t) {
      uint32_t s = (uint32_t)lane + ((uint32_t)t << 6);
      uint32_t o0, o1;
      threefry2x32_1234(0u, base + s, o0, o1);
      uint32_t bits = o0 ^ o1;
      unsigned long long k =
          ((unsigned long long)(bits >> 9) << 32) | (0xFFFFFFFFu - s);
      if (b == 15 && s == (uint32_t)r) k = 0ull;
      keys[t] = k;
    }

    uint32_t idx[5];
    top5_mask(keys, idx);

#pragma unroll
    for (int n = 0; n < 5; ++n)
      if (lane == n) neg_idx[(size_t)row * 5 + n] = idx[n];
  }
}

// ---------------------------------------------------------------------------
// Kernel B: pure gather. one wave per score-row; read 5 indices from ws,
// copy out0 row (idx*16+15) -> out2 row (row*5+n). ~84 MB writes, L2 reads.
// ---------------------------------------------------------------------------
__global__ __launch_bounds__(256) void kB(const float* __restrict__ out0,
                                          const uint32_t* __restrict__ neg_idx,
                                          float* __restrict__ out2) {
  const int tid = blockIdx.x * blockDim.x + threadIdx.x;
  const int lane = threadIdx.x & 63;
  const int row = tid >> 6;          // r*16 + b

#pragma unroll
  for (int n = 0; n < 5; ++n) {
    uint32_t idx = neg_idx[(size_t)row * 5 + n];   // wave-uniform
    const f32x4* src = (const f32x4*)(out0 + ((size_t)idx * B_DIM + 15) * D_DIM);
    f32x4* dst = (f32x4*)(out2 + ((size_t)row * 5 + n) * D_DIM);
    __builtin_nontemporal_store(src[lane], &dst[lane]);
  }
}

// ---------------------------------------------------------------------------
extern "C" void kernel_launch(void* const* d_in, const int* in_sizes, int n_in,
                              void* d_out, int out_size, void* d_ws, size_t ws_size,
                              hipStream_t stream) {
  (void)in_sizes; (void)n_in; (void)ws_size; (void)out_size;
  const float* vit = (const float*)d_in[0];  // (16, 256, 1024)
  const float* lag = (const float*)d_in[1];  // (16, 20, 256)
  const float* map = (const float*)d_in[2];  // (16, 20, 1024)
  float* out = (float*)d_out;
  float* out0 = out;                                   // (1024,16,256)
  float* out1 = out + 4194304;                         // (1024,16,4,256)
  float* out2 = out + 4194304 + 16777216;              // (1024,16,5,256)
  uint32_t* neg_idx = (uint32_t*)d_ws;                 // 16384*5 u32 = 320 KB

  kA<<<12288, 256, 0, stream>>>(vit, lag, map, out0, out1, neg_idx);
  kB<<<4096, 256, 0, stream>>>(out0, neg_idx, out2);  // stream-ordered dep
}

// Round 6
// 212.826 us; speedup vs baseline: 1.0856x; 1.0856x over previous
//
#include <hip/hip_runtime.h>
#include <stdint.h>

// Problem constants
#define R_DIM 1024
#define B_DIM 16
#define D_DIM 256
#define S_DIM 20

typedef float f32x4 __attribute__((ext_vector_type(4)));

// ---------------------------------------------------------------------------
// JAX threefry2x32, key = [0, 1234], partitionable counter scheme:
// for flat index i: x0 = 0, x1 = i; bits = o0 ^ o1.
// ---------------------------------------------------------------------------
__device__ __forceinline__ void threefry2x32_1234(uint32_t x0, uint32_t x1,
                                                  uint32_t& o0, uint32_t& o1) {
  const uint32_t ks1 = 1234u;
  const uint32_t ks2 = 1234u ^ 0x1BD11BDAu;
  x1 += ks1;  // x0 += ks0 (=0)
#define TF_ROUND(r) { x0 += x1; x1 = (x1 << (r)) | (x1 >> (32 - (r))); x1 ^= x0; }
  TF_ROUND(13) TF_ROUND(15) TF_ROUND(26) TF_ROUND(6)
  x0 += ks1; x1 += ks2 + 1u;
  TF_ROUND(17) TF_ROUND(29) TF_ROUND(16) TF_ROUND(24)
  x0 += ks2; x1 += 2u;  // + ks0 (=0)
  TF_ROUND(13) TF_ROUND(15) TF_ROUND(26) TF_ROUND(6)
  x1 += ks1 + 3u;       // x0 += ks0 (=0)
  TF_ROUND(17) TF_ROUND(29) TF_ROUND(16) TF_ROUND(24)
  x0 += ks1; x1 += ks2 + 4u;
  TF_ROUND(13) TF_ROUND(15) TF_ROUND(26) TF_ROUND(6)
  x0 += ks2; x1 += 5u;  // + ks0 (=0)
#undef TF_ROUND
  o0 = x0; o1 = x1;
}

// 64-lane butterfly max of a uint64 key
__device__ __forceinline__ unsigned long long wave_max_u64(unsigned long long v) {
#pragma unroll
  for (int off = 1; off < 64; off <<= 1) {
    unsigned long long o = __shfl_xor(v, off, 64);
    v = (o > v) ? o : v;
  }
  return v;
}

__device__ __forceinline__ void top5_mask(unsigned long long* keys, uint32_t* idx) {
#pragma unroll
  for (int n = 0; n < 5; ++n) {
    unsigned long long lm = keys[0];
#pragma unroll
    for (int t = 1; t < 16; ++t) lm = (keys[t] > lm) ? keys[t] : lm;
    unsigned long long g = wave_max_u64(lm);
    idx[n] = 0xFFFFFFFFu - (uint32_t)g;
#pragma unroll
    for (int t = 0; t < 16; ++t)
      if (keys[t] == g) keys[t] = 0ull;
  }
}

// ---------------------------------------------------------------------------
// kT: transpose only the vit[15] slice (256x1024 -> 1024x256) into d_ws.
// 256 blocks of 256 threads; ~1 MB, stays L2-hot for kMain's out2 gathers.
// ---------------------------------------------------------------------------
__global__ __launch_bounds__(256) void kT(const float* __restrict__ vit,
                                          float* __restrict__ vit15T) {
  __shared__ float tile[32][33];
  const int bx = blockIdx.x & 31;        // r-tile
  const int by = blockIdx.x >> 5;        // d-tile (0..7)
  const int r0 = bx * 32, d0 = by * 32;
  const int tx = threadIdx.x & 31, ty = threadIdx.x >> 5;
  const float* src = vit + (size_t)15 * D_DIM * R_DIM;
#pragma unroll
  for (int i = 0; i < 4; ++i) {
    int d = d0 + ty + i * 8;
    tile[ty + i * 8][tx] = src[(size_t)d * R_DIM + r0 + tx];
  }
  __syncthreads();
#pragma unroll
  for (int i = 0; i < 4; ++i) {
    int r = r0 + ty + i * 8;
    vit15T[(size_t)r * D_DIM + d0 + tx] = tile[tx][ty + i * 8];  // cached: re-read 84x
  }
}

// ---------------------------------------------------------------------------
// kMain: 12288 blocks, role = blockIdx % 3 (striped so VALU-bound threefry
// blocks are co-resident with memory-bound transpose/gather blocks):
//   role 0 (4096): threefry top5 per score-row -> gather out2 from vit15T
//   role 1 (4096): transpose out0[r][b][d] = vit[b][d][r]
//   role 2 (4096): top4 over lag_vit_map -> gather out1 from lag_feature
// ---------------------------------------------------------------------------
__global__ __launch_bounds__(256) void kMain(const float* __restrict__ vit,
                                             const float* __restrict__ lag_feature,
                                             const float* __restrict__ lag_vit_map,
                                             const float* __restrict__ vit15T,
                                             float* __restrict__ out0,
                                             float* __restrict__ out1,
                                             float* __restrict__ out2) {
  const int role = blockIdx.x % 3;
  const int u = blockIdx.x / 3;          // 0..4095 within each role
  const int lane = threadIdx.x & 63;
  const int wv = threadIdx.x >> 6;       // wave in block, 0..3

  if (role == 0) {
    // ---- threefry + top5 + out2 gather: one wave per score-row ----
    const int row = u * 4 + wv;          // r*16 + b
    const int r = row >> 4, b = row & 15;

    unsigned long long keys[16];
    const uint32_t base = (uint32_t)row * 1024u;
#pragma unroll
    for (int t = 0; t < 16; ++t) {
      uint32_t s = (uint32_t)lane + ((uint32_t)t << 6);
      uint32_t o0, o1;
      threefry2x32_1234(0u, base + s, o0, o1);
      uint32_t bits = o0 ^ o1;
      unsigned long long k =
          ((unsigned long long)(bits >> 9) << 32) | (0xFFFFFFFFu - s);
      if (b == 15 && s == (uint32_t)r) k = 0ull;
      keys[t] = k;
    }

    uint32_t idx[5];
    top5_mask(keys, idx);

#pragma unroll
    for (int n = 0; n < 5; ++n) {
      const f32x4* src = (const f32x4*)(vit15T + (size_t)idx[n] * D_DIM);
      f32x4* dst = (f32x4*)(out2 + ((size_t)row * 5 + n) * D_DIM);
      __builtin_nontemporal_store(src[lane], &dst[lane]);
    }
  } else if (role == 1) {
    // ---- transpose: 32x32 tile; u -> (b, d-tile, r-tile) ----
    __shared__ float tile[32][33];
    const int b = u >> 8;                // 0..15
    const int t8 = u & 255;
    const int bx = t8 & 31;              // r-tile
    const int by = t8 >> 5;              // d-tile
    const int r0 = bx * 32, d0 = by * 32;
    const int tx = threadIdx.x & 31, ty = threadIdx.x >> 5;
    const float* src = vit + (size_t)b * D_DIM * R_DIM;
#pragma unroll
    for (int i = 0; i < 4; ++i) {
      int d = d0 + ty + i * 8;
      tile[ty + i * 8][tx] = src[(size_t)d * R_DIM + r0 + tx];
    }
    __syncthreads();
#pragma unroll
    for (int i = 0; i < 4; ++i) {
      int r = r0 + ty + i * 8;
      __builtin_nontemporal_store(tile[tx][ty + i * 8],
                                  &out0[((size_t)r * B_DIM + b) * D_DIM + d0 + tx]);
    }
  } else {
    // ---- top4 over lag_vit_map + out1 gather: one wave per (r,b) row ----
    const int row = u * 4 + wv;          // r*16 + b
    const int r = row >> 4;
    const int b = row & 15;

    unsigned long long key = 0ull;
    if (lane < S_DIM) {
      float f = lag_vit_map[((size_t)b * S_DIM + lane) * R_DIM + r];
      uint32_t uu = __float_as_uint(f);
      uint32_t ok = uu ^ (uint32_t)(((int32_t)uu >> 31) | 0x80000000u);
      key = ((unsigned long long)ok << 32) | (0xFFFFFFFFu - (uint32_t)lane);
    }

    uint32_t cols[4];
#pragma unroll
    for (int k = 0; k < 4; ++k) {
      unsigned long long m = wave_max_u64(key);
      cols[k] = 0xFFFFFFFFu - (uint32_t)m;
      if (key == m) key = 0ull;
    }

#pragma unroll
    for (int k = 0; k < 4; ++k) {
      const f32x4* src = (const f32x4*)(lag_feature + ((size_t)b * S_DIM + cols[k]) * D_DIM);
      f32x4* dst = (f32x4*)(out1 + ((size_t)row * 4 + k) * D_DIM);
      __builtin_nontemporal_store(src[lane], &dst[lane]);
    }
  }
}

// ---------------------------------------------------------------------------
extern "C" void kernel_launch(void* const* d_in, const int* in_sizes, int n_in,
                              void* d_out, int out_size, void* d_ws, size_t ws_size,
                              hipStream_t stream) {
  (void)in_sizes; (void)n_in; (void)ws_size; (void)out_size;
  const float* vit = (const float*)d_in[0];  // (16, 256, 1024)
  const float* lag = (const float*)d_in[1];  // (16, 20, 256)
  const float* map = (const float*)d_in[2];  // (16, 20, 1024)
  float* out = (float*)d_out;
  float* out0 = out;                                   // (1024,16,256)
  float* out1 = out + 4194304;                         // (1024,16,4,256)
  float* out2 = out + 4194304 + 16777216;              // (1024,16,5,256)
  float* vit15T = (float*)d_ws;                        // (1024,256) = 1 MB

  kT<<<256, 256, 0, stream>>>(vit, vit15T);
  kMain<<<12288, 256, 0, stream>>>(vit, lag, map, vit15T, out0, out1, out2);
}